// Round 1
// baseline (1121.154 us; speedup 1.0000x reference)
//
#include <hip/hip_runtime.h>

#define N_NODES 50000
#define N_EDGES 600000
#define D 128

// ---------------------------------------------------------------------------
// Kernel 1: zero d_out (prop accumulator lives in d_out; harness poisons it)
// ---------------------------------------------------------------------------
__global__ void zero_kernel(float4* __restrict__ out, int n4) {
    int i = blockIdx.x * blockDim.x + threadIdx.x;
    int stride = gridDim.x * blockDim.x;
    for (; i < n4; i += stride) out[i] = make_float4(0.f, 0.f, 0.f, 0.f);
}

// ---------------------------------------------------------------------------
// Kernel 2: scatter  prop[dst] += edge_emb[w] * x[src]
// 32 threads per edge, one float4 (16B) per thread -> 512B contiguous per row.
// ---------------------------------------------------------------------------
__global__ __launch_bounds__(256) void scatter_kernel(
    const float* __restrict__ x,
    const float* __restrict__ emb,
    const int*   __restrict__ ei,   // [2, E] flat: src = ei[e], dst = ei[E+e]
    const int*   __restrict__ ew,   // [E]
    float*       __restrict__ prop) // [N, D] (aliases d_out)
{
    int gid = blockIdx.x * blockDim.x + threadIdx.x;
    int e = gid >> 5;
    if (e >= N_EDGES) return;
    int d4 = (gid & 31) * 4;

    int src = ei[e];
    int dst = ei[N_EDGES + e];
    int w   = ew[e];

    float4 ev = *(const float4*)(emb + (size_t)w * D + d4);
    float4 xv = *(const float4*)(x + (size_t)src * D + d4);

    float* p = prop + (size_t)dst * D + d4;
    atomicAdd(p + 0, ev.x * xv.x);
    atomicAdd(p + 1, ev.y * xv.y);
    atomicAdd(p + 2, ev.z * xv.z);
    atomicAdd(p + 3, ev.w * xv.w);
}

// ---------------------------------------------------------------------------
// Kernel 3: transpose W_l, W_r (128x128) into ws so GEMM reads W^T coalesced.
// One-time tiny kernel (~32K elements).
// ---------------------------------------------------------------------------
__global__ void transpose_w(const float* __restrict__ wl,
                            const float* __restrict__ wr,
                            float* __restrict__ wtl,
                            float* __restrict__ wtr)
{
    int t = blockIdx.x * blockDim.x + threadIdx.x;
    if (t >= D * D) return;
    int j = t >> 7;      // row of W  (output col)
    int k = t & 127;     // col of W  (reduction dim)
    wtl[k * D + j] = wl[t];
    wtr[k * D + j] = wr[t];
}

// ---------------------------------------------------------------------------
// Kernel 4: out = x @ W_l^T + b_l + prop @ W_r^T + b_r        (in-place on
// d_out: each block stages its own 32 rows of prop (=d_out) into LDS first,
// then overwrites only those rows).
//
// Block: 256 threads = 32 col-groups (4 cols each) x 8 row-groups (4 rows).
// Per-thread 4x4 register tile, k-loop reads W^T rows coalesced (512B/wave,
// broadcast across the two half-waves), x/prop via LDS scalar broadcast.
// ---------------------------------------------------------------------------
__global__ __launch_bounds__(256) void gemm_kernel(
    const float* __restrict__ x,
    float*       __restrict__ out,   // holds prop on entry, result on exit
    const float* __restrict__ wtl,   // [k][j] = W_l[j][k]
    const float* __restrict__ wtr,
    const float* __restrict__ bl,
    const float* __restrict__ br)
{
    __shared__ float xs[32][D];
    __shared__ float ps[32][D];

    int tid  = threadIdx.x;
    int row0 = blockIdx.x * 32;

    // stage 32 rows of x and prop into LDS (guarded; zero-pad tail)
    for (int i = tid; i < 32 * 32; i += 256) {
        int r  = i >> 5;
        int c4 = (i & 31) * 4;
        int row = row0 + r;
        float4 xv = make_float4(0.f, 0.f, 0.f, 0.f);
        float4 pv = xv;
        if (row < N_NODES) {
            xv = *(const float4*)(x   + (size_t)row * D + c4);
            pv = *(const float4*)(out + (size_t)row * D + c4);
        }
        *(float4*)&xs[r][c4] = xv;
        *(float4*)&ps[r][c4] = pv;
    }
    __syncthreads();

    int jc = (tid & 31) * 4;        // first of 4 output columns
    int rg = (tid >> 5) * 4;        // first of 4 rows within the tile

    float acc[4][4];
    {
        float b0 = bl[jc + 0] + br[jc + 0];
        float b1 = bl[jc + 1] + br[jc + 1];
        float b2 = bl[jc + 2] + br[jc + 2];
        float b3 = bl[jc + 3] + br[jc + 3];
#pragma unroll
        for (int r = 0; r < 4; r++) {
            acc[r][0] = b0; acc[r][1] = b1; acc[r][2] = b2; acc[r][3] = b3;
        }
    }

#pragma unroll 8
    for (int k = 0; k < D; k++) {
        float4 wl = *(const float4*)(wtl + k * D + jc);
        float4 wr = *(const float4*)(wtr + k * D + jc);
#pragma unroll
        for (int r = 0; r < 4; r++) {
            float xv = xs[rg + r][k];   // LDS broadcast
            float pv = ps[rg + r][k];
            acc[r][0] += xv * wl.x + pv * wr.x;
            acc[r][1] += xv * wl.y + pv * wr.y;
            acc[r][2] += xv * wl.z + pv * wr.z;
            acc[r][3] += xv * wl.w + pv * wr.w;
        }
    }

#pragma unroll
    for (int r = 0; r < 4; r++) {
        int row = row0 + rg + r;
        if (row < N_NODES) {
            float4 v = make_float4(acc[r][0], acc[r][1], acc[r][2], acc[r][3]);
            *(float4*)(out + (size_t)row * D + jc) = v;
        }
    }
}

// ---------------------------------------------------------------------------
extern "C" void kernel_launch(void* const* d_in, const int* in_sizes, int n_in,
                              void* d_out, int out_size, void* d_ws, size_t ws_size,
                              hipStream_t stream) {
    const float* x    = (const float*)d_in[0];   // [N, D]
    const float* emb  = (const float*)d_in[1];   // [10, D]
    const float* W_l  = (const float*)d_in[2];   // [D, D]
    const float* b_l  = (const float*)d_in[3];   // [D]
    const float* W_r  = (const float*)d_in[4];   // [D, D]
    const float* b_r  = (const float*)d_in[5];   // [D]
    const int*   ei   = (const int*)d_in[6];     // [2, E]
    const int*   ew   = (const int*)d_in[7];     // [E]
    // d_in[8] = cat_list, unused by the active path

    float* out = (float*)d_out;
    float* wtl = (float*)d_ws;           // 64 KB
    float* wtr = wtl + D * D;            // 64 KB  (ws needs >= 128 KB)

    // 1. zero prop accumulator (in d_out)
    int n4 = N_NODES * D / 4;
    zero_kernel<<<(n4 + 255) / 256, 256, 0, stream>>>((float4*)out, n4);

    // 2. transpose weights into ws
    transpose_w<<<(D * D + 255) / 256, 256, 0, stream>>>(W_l, W_r, wtl, wtr);

    // 3. scatter-sum messages into d_out
    {
        long long work = (long long)N_EDGES * 32;
        int blocks = (int)((work + 255) / 256);
        scatter_kernel<<<blocks, 256, 0, stream>>>(x, emb, ei, ew, out);
    }

    // 4. fused dual GEMM + bias, in-place on d_out
    gemm_kernel<<<(N_NODES + 31) / 32, 256, 0, stream>>>(x, out, wtl, wtr, b_l, b_r);
}

// Round 2
// 337.632 us; speedup vs baseline: 3.3206x; 3.3206x over previous
//
#include <hip/hip_runtime.h>

#define N_NODES 50000
#define N_EDGES 600000
#define D 128

// ============================== CSR-build path ==============================

__global__ void zero_ints(int* __restrict__ p, int n) {
    int i = blockIdx.x * blockDim.x + threadIdx.x;
    if (i < n) p[i] = 0;
}

// histogram of destination nodes
__global__ __launch_bounds__(256) void hist_kernel(
    const int* __restrict__ ei, int* __restrict__ counts)
{
    int e = blockIdx.x * blockDim.x + threadIdx.x;
    if (e >= N_EDGES) return;
    atomicAdd(&counts[ei[N_EDGES + e]], 1);
}

// single-block exclusive scan of 50K counts -> offs[N+1], and copy to woff
__global__ __launch_bounds__(1024) void scan_kernel(
    const int* __restrict__ counts,
    int* __restrict__ offs,
    int* __restrict__ woff)
{
    __shared__ int part[1024];
    const int CH = (N_NODES + 1023) / 1024;   // 49
    int t  = threadIdx.x;
    int lo = t * CH;
    int hi = lo + CH; if (hi > N_NODES) hi = N_NODES;
    if (lo > N_NODES) lo = N_NODES;

    int s = 0;
    for (int i = lo; i < hi; i++) s += counts[i];
    part[t] = s;
    __syncthreads();
    // Hillis-Steele inclusive scan over 1024 partials
    for (int off = 1; off < 1024; off <<= 1) {
        int v = (t >= off) ? part[t - off] : 0;
        __syncthreads();
        part[t] += v;
        __syncthreads();
    }
    int run = (t > 0) ? part[t - 1] : 0;
    for (int i = lo; i < hi; i++) {
        offs[i] = run; woff[i] = run;
        run += counts[i];
    }
    if (t == 1023) offs[N_NODES] = run;   // == N_EDGES
}

// compact edges into dst-sorted order; pack (src | w<<16) into u32
__global__ __launch_bounds__(256) void pack_kernel(
    const int* __restrict__ ei,
    const int* __restrict__ ew,
    int* __restrict__ woff,
    unsigned* __restrict__ packed)
{
    int e = blockIdx.x * blockDim.x + threadIdx.x;
    if (e >= N_EDGES) return;
    int dst = ei[N_EDGES + e];
    int pos = atomicAdd(&woff[dst], 1);
    packed[pos] = (unsigned)ei[e] | ((unsigned)ew[e] << 16);
}

// one 64-lane wave per node, float2 per lane; prop row written exactly once
__global__ __launch_bounds__(256) void aggregate_kernel(
    const float* __restrict__ x,
    const float* __restrict__ emb,
    const int* __restrict__ offs,
    const unsigned* __restrict__ packed,
    float* __restrict__ prop)   // aliases d_out
{
    int node = blockIdx.x * 4 + (threadIdx.x >> 6);
    if (node >= N_NODES) return;
    int c = (threadIdx.x & 63) * 2;

    int beg = offs[node], end = offs[node + 1];
    float2 acc = make_float2(0.f, 0.f);
    for (int i = beg; i < end; i++) {
        unsigned p = packed[i];
        float2 ev = *(const float2*)(emb + (size_t)(p >> 16) * D + c);
        float2 xv = *(const float2*)(x   + (size_t)(p & 0xFFFFu) * D + c);
        acc.x += ev.x * xv.x;
        acc.y += ev.y * xv.y;
    }
    *(float2*)(prop + (size_t)node * D + c) = acc;
}

// ============================ fallback (atomic) =============================

__global__ void zero_kernel(float4* __restrict__ out, int n4) {
    int i = blockIdx.x * blockDim.x + threadIdx.x;
    int stride = gridDim.x * blockDim.x;
    for (; i < n4; i += stride) out[i] = make_float4(0.f, 0.f, 0.f, 0.f);
}

__global__ __launch_bounds__(256) void scatter_kernel(
    const float* __restrict__ x,
    const float* __restrict__ emb,
    const int*   __restrict__ ei,
    const int*   __restrict__ ew,
    float*       __restrict__ prop)
{
    int gid = blockIdx.x * blockDim.x + threadIdx.x;
    int e = gid >> 5;
    if (e >= N_EDGES) return;
    int d4 = (gid & 31) * 4;
    int src = ei[e];
    int dst = ei[N_EDGES + e];
    int w   = ew[e];
    float4 ev = *(const float4*)(emb + (size_t)w * D + d4);
    float4 xv = *(const float4*)(x + (size_t)src * D + d4);
    float* p = prop + (size_t)dst * D + d4;
    atomicAdd(p + 0, ev.x * xv.x);
    atomicAdd(p + 1, ev.y * xv.y);
    atomicAdd(p + 2, ev.z * xv.z);
    atomicAdd(p + 3, ev.w * xv.w);
}

// ================================ GEMM ======================================

__global__ void transpose_w(const float* __restrict__ wl,
                            const float* __restrict__ wr,
                            float* __restrict__ wtl,
                            float* __restrict__ wtr)
{
    int t = blockIdx.x * blockDim.x + threadIdx.x;
    if (t >= D * D) return;
    int j = t >> 7;
    int k = t & 127;
    wtl[k * D + j] = wl[t];
    wtr[k * D + j] = wr[t];
}

__global__ __launch_bounds__(256) void gemm_kernel(
    const float* __restrict__ x,
    float*       __restrict__ out,   // prop on entry, result on exit
    const float* __restrict__ wtl,
    const float* __restrict__ wtr,
    const float* __restrict__ bl,
    const float* __restrict__ br)
{
    __shared__ float xs[32][D];
    __shared__ float ps[32][D];

    int tid  = threadIdx.x;
    int row0 = blockIdx.x * 32;

    for (int i = tid; i < 32 * 32; i += 256) {
        int r  = i >> 5;
        int c4 = (i & 31) * 4;
        int row = row0 + r;
        float4 xv = make_float4(0.f, 0.f, 0.f, 0.f);
        float4 pv = xv;
        if (row < N_NODES) {
            xv = *(const float4*)(x   + (size_t)row * D + c4);
            pv = *(const float4*)(out + (size_t)row * D + c4);
        }
        *(float4*)&xs[r][c4] = xv;
        *(float4*)&ps[r][c4] = pv;
    }
    __syncthreads();

    int jc = (tid & 31) * 4;
    int rg = (tid >> 5) * 4;

    float acc[4][4];
    {
        float b0 = bl[jc + 0] + br[jc + 0];
        float b1 = bl[jc + 1] + br[jc + 1];
        float b2 = bl[jc + 2] + br[jc + 2];
        float b3 = bl[jc + 3] + br[jc + 3];
#pragma unroll
        for (int r = 0; r < 4; r++) {
            acc[r][0] = b0; acc[r][1] = b1; acc[r][2] = b2; acc[r][3] = b3;
        }
    }

#pragma unroll 8
    for (int k = 0; k < D; k++) {
        float4 wl = *(const float4*)(wtl + k * D + jc);
        float4 wr = *(const float4*)(wtr + k * D + jc);
#pragma unroll
        for (int r = 0; r < 4; r++) {
            float xv = xs[rg + r][k];
            float pv = ps[rg + r][k];
            acc[r][0] += xv * wl.x + pv * wr.x;
            acc[r][1] += xv * wl.y + pv * wr.y;
            acc[r][2] += xv * wl.z + pv * wr.z;
            acc[r][3] += xv * wl.w + pv * wr.w;
        }
    }

#pragma unroll
    for (int r = 0; r < 4; r++) {
        int row = row0 + rg + r;
        if (row < N_NODES) {
            float4 v = make_float4(acc[r][0], acc[r][1], acc[r][2], acc[r][3]);
            *(float4*)(out + (size_t)row * D + jc) = v;
        }
    }
}

// ============================================================================
extern "C" void kernel_launch(void* const* d_in, const int* in_sizes, int n_in,
                              void* d_out, int out_size, void* d_ws, size_t ws_size,
                              hipStream_t stream) {
    const float* x    = (const float*)d_in[0];
    const float* emb  = (const float*)d_in[1];
    const float* W_l  = (const float*)d_in[2];
    const float* b_l  = (const float*)d_in[3];
    const float* W_r  = (const float*)d_in[4];
    const float* b_r  = (const float*)d_in[5];
    const int*   ei   = (const int*)d_in[6];
    const int*   ew   = (const int*)d_in[7];

    float* out = (float*)d_out;

    // workspace layout
    char* ws = (char*)d_ws;
    float*    wtl    = (float*)ws;                      ws += D * D * sizeof(float);
    float*    wtr    = (float*)ws;                      ws += D * D * sizeof(float);
    int*      counts = (int*)ws;                        ws += N_NODES * sizeof(int);
    int*      offs   = (int*)ws;                        ws += (N_NODES + 1) * sizeof(int);
    int*      woff   = (int*)ws;                        ws += N_NODES * sizeof(int);
    unsigned* packed = (unsigned*)ws;                   ws += N_EDGES * sizeof(unsigned);
    size_t needed = (size_t)(ws - (char*)d_ws);

    transpose_w<<<(D * D + 255) / 256, 256, 0, stream>>>(W_l, W_r, wtl, wtr);

    if (ws_size >= needed) {
        // CSR build + gather aggregate (no float atomics)
        zero_ints<<<(N_NODES + 255) / 256, 256, 0, stream>>>(counts, N_NODES);
        hist_kernel<<<(N_EDGES + 255) / 256, 256, 0, stream>>>(ei, counts);
        scan_kernel<<<1, 1024, 0, stream>>>(counts, offs, woff);
        pack_kernel<<<(N_EDGES + 255) / 256, 256, 0, stream>>>(ei, ew, woff, packed);
        aggregate_kernel<<<(N_NODES + 3) / 4, 256, 0, stream>>>(x, emb, offs, packed, out);
    } else {
        // fallback: atomic scatter into d_out
        int n4 = N_NODES * D / 4;
        zero_kernel<<<(n4 + 255) / 256, 256, 0, stream>>>((float4*)out, n4);
        long long work = (long long)N_EDGES * 32;
        scatter_kernel<<<(int)((work + 255) / 256), 256, 0, stream>>>(x, emb, ei, ew, out);
    }

    gemm_kernel<<<(N_NODES + 31) / 32, 256, 0, stream>>>(x, out, wtl, wtr, b_l, b_r);
}

// Round 3
// 237.337 us; speedup vs baseline: 4.7239x; 1.4226x over previous
//
#include <hip/hip_runtime.h>

#define N_NODES 50000
#define N_EDGES 600000
#define D 128
#define SCAN_BLOCKS ((N_NODES + 255) / 256)   // 196

// ============================== CSR-build path ==============================

__global__ void zero_ints(int* __restrict__ p, int n) {
    int i = blockIdx.x * blockDim.x + threadIdx.x;
    if (i < n) p[i] = 0;
}

// histogram of destination nodes
__global__ __launch_bounds__(256) void hist_kernel(
    const int* __restrict__ ei, int* __restrict__ counts)
{
    int e = blockIdx.x * blockDim.x + threadIdx.x;
    if (e >= N_EDGES) return;
    atomicAdd(&counts[ei[N_EDGES + e]], 1);
}

// ---- 3-phase exclusive scan of counts[N_NODES] -> offs[N+1], woff[N] ----

__global__ __launch_bounds__(256) void scan_phase1(
    const int* __restrict__ counts, int* __restrict__ blockSums)
{
    int i = blockIdx.x * 256 + threadIdx.x;
    int v = (i < N_NODES) ? counts[i] : 0;
#pragma unroll
    for (int off = 32; off > 0; off >>= 1) v += __shfl_down(v, off, 64);
    __shared__ int wsum[4];
    int lane = threadIdx.x & 63, wid = threadIdx.x >> 6;
    if (lane == 0) wsum[wid] = v;
    __syncthreads();
    if (threadIdx.x == 0)
        blockSums[blockIdx.x] = wsum[0] + wsum[1] + wsum[2] + wsum[3];
}

__global__ __launch_bounds__(256) void scan_phase2(
    const int* __restrict__ blockSums, int* __restrict__ blockOffs,
    int* __restrict__ offs)
{
    __shared__ int sh[256];
    int t = threadIdx.x;
    int v = (t < SCAN_BLOCKS) ? blockSums[t] : 0;
    sh[t] = v;
    __syncthreads();
    for (int off = 1; off < 256; off <<= 1) {
        int u = (t >= off) ? sh[t - off] : 0;
        __syncthreads();
        sh[t] += u;
        __syncthreads();
    }
    if (t < SCAN_BLOCKS) blockOffs[t] = sh[t] - v;   // exclusive
    if (t == 0) offs[N_NODES] = N_EDGES;
}

__global__ __launch_bounds__(256) void scan_phase3(
    const int* __restrict__ counts,
    const int* __restrict__ blockOffs,
    int* __restrict__ offs, int* __restrict__ woff)
{
    int t = threadIdx.x;
    int i = blockIdx.x * 256 + t;
    int v = (i < N_NODES) ? counts[i] : 0;
    int lane = t & 63, wid = t >> 6;
    int s = v;
#pragma unroll
    for (int off = 1; off < 64; off <<= 1) {
        int u = __shfl_up(s, off, 64);
        if (lane >= off) s += u;
    }
    __shared__ int wsum[4];
    if (lane == 63) wsum[wid] = s;
    __syncthreads();
    int wadd = 0;
    for (int w = 0; w < wid; w++) wadd += wsum[w];
    if (i < N_NODES) {
        int excl = blockOffs[blockIdx.x] + s + wadd - v;
        offs[i] = excl;
        woff[i] = excl;
    }
}

// compact edges into dst-sorted order; pack (src | w<<16) into u32
__global__ __launch_bounds__(256) void pack_kernel(
    const int* __restrict__ ei,
    const int* __restrict__ ew,
    int* __restrict__ woff,
    unsigned* __restrict__ packed)
{
    int e = blockIdx.x * blockDim.x + threadIdx.x;
    if (e >= N_EDGES) return;
    int dst = ei[N_EDGES + e];
    int pos = atomicAdd(&woff[dst], 1);
    packed[pos] = (unsigned)ei[e] | ((unsigned)ew[e] << 16);
}

// one 64-lane wave per node, float2 per lane; prop row written exactly once
__global__ __launch_bounds__(256) void aggregate_kernel(
    const float* __restrict__ x,
    const float* __restrict__ emb,
    const int* __restrict__ offs,
    const unsigned* __restrict__ packed,
    float* __restrict__ prop)   // aliases d_out
{
    int node = blockIdx.x * 4 + (threadIdx.x >> 6);
    if (node >= N_NODES) return;
    int c = (threadIdx.x & 63) * 2;

    int beg = offs[node], end = offs[node + 1];
    float2 acc = make_float2(0.f, 0.f);
    for (int i = beg; i < end; i++) {
        unsigned p = packed[i];
        float2 ev = *(const float2*)(emb + (size_t)(p >> 16) * D + c);
        float2 xv = *(const float2*)(x   + (size_t)(p & 0xFFFFu) * D + c);
        acc.x += ev.x * xv.x;
        acc.y += ev.y * xv.y;
    }
    *(float2*)(prop + (size_t)node * D + c) = acc;
}

// ============================ fallback (atomic) =============================

__global__ void zero_kernel(float4* __restrict__ out, int n4) {
    int i = blockIdx.x * blockDim.x + threadIdx.x;
    int stride = gridDim.x * blockDim.x;
    for (; i < n4; i += stride) out[i] = make_float4(0.f, 0.f, 0.f, 0.f);
}

__global__ __launch_bounds__(256) void scatter_kernel(
    const float* __restrict__ x,
    const float* __restrict__ emb,
    const int*   __restrict__ ei,
    const int*   __restrict__ ew,
    float*       __restrict__ prop)
{
    int gid = blockIdx.x * blockDim.x + threadIdx.x;
    int e = gid >> 5;
    if (e >= N_EDGES) return;
    int d4 = (gid & 31) * 4;
    int src = ei[e];
    int dst = ei[N_EDGES + e];
    int w   = ew[e];
    float4 ev = *(const float4*)(emb + (size_t)w * D + d4);
    float4 xv = *(const float4*)(x + (size_t)src * D + d4);
    float* p = prop + (size_t)dst * D + d4;
    atomicAdd(p + 0, ev.x * xv.x);
    atomicAdd(p + 1, ev.y * xv.y);
    atomicAdd(p + 2, ev.z * xv.z);
    atomicAdd(p + 3, ev.w * xv.w);
}

// ================================ GEMM ======================================

__global__ void transpose_w(const float* __restrict__ wl,
                            const float* __restrict__ wr,
                            float* __restrict__ wtl,
                            float* __restrict__ wtr)
{
    int t = blockIdx.x * blockDim.x + threadIdx.x;
    if (t >= D * D) return;
    int j = t >> 7;
    int k = t & 127;
    wtl[k * D + j] = wl[t];
    wtr[k * D + j] = wr[t];
}

__global__ __launch_bounds__(256) void gemm_kernel(
    const float* __restrict__ x,
    float*       __restrict__ out,   // prop on entry, result on exit
    const float* __restrict__ wtl,
    const float* __restrict__ wtr,
    const float* __restrict__ bl,
    const float* __restrict__ br)
{
    __shared__ float xs[32][D];
    __shared__ float ps[32][D];

    int tid  = threadIdx.x;
    int row0 = blockIdx.x * 32;

    for (int i = tid; i < 32 * 32; i += 256) {
        int r  = i >> 5;
        int c4 = (i & 31) * 4;
        int row = row0 + r;
        float4 xv = make_float4(0.f, 0.f, 0.f, 0.f);
        float4 pv = xv;
        if (row < N_NODES) {
            xv = *(const float4*)(x   + (size_t)row * D + c4);
            pv = *(const float4*)(out + (size_t)row * D + c4);
        }
        *(float4*)&xs[r][c4] = xv;
        *(float4*)&ps[r][c4] = pv;
    }
    __syncthreads();

    int jc = (tid & 31) * 4;
    int rg = (tid >> 5) * 4;

    float acc[4][4];
    {
        float b0 = bl[jc + 0] + br[jc + 0];
        float b1 = bl[jc + 1] + br[jc + 1];
        float b2 = bl[jc + 2] + br[jc + 2];
        float b3 = bl[jc + 3] + br[jc + 3];
#pragma unroll
        for (int r = 0; r < 4; r++) {
            acc[r][0] = b0; acc[r][1] = b1; acc[r][2] = b2; acc[r][3] = b3;
        }
    }

#pragma unroll 8
    for (int k = 0; k < D; k++) {
        float4 wl = *(const float4*)(wtl + k * D + jc);
        float4 wr = *(const float4*)(wtr + k * D + jc);
#pragma unroll
        for (int r = 0; r < 4; r++) {
            float xv = xs[rg + r][k];
            float pv = ps[rg + r][k];
            acc[r][0] += xv * wl.x + pv * wr.x;
            acc[r][1] += xv * wl.y + pv * wr.y;
            acc[r][2] += xv * wl.z + pv * wr.z;
            acc[r][3] += xv * wl.w + pv * wr.w;
        }
    }

#pragma unroll
    for (int r = 0; r < 4; r++) {
        int row = row0 + rg + r;
        if (row < N_NODES) {
            float4 v = make_float4(acc[r][0], acc[r][1], acc[r][2], acc[r][3]);
            *(float4*)(out + (size_t)row * D + jc) = v;
        }
    }
}

// ============================================================================
extern "C" void kernel_launch(void* const* d_in, const int* in_sizes, int n_in,
                              void* d_out, int out_size, void* d_ws, size_t ws_size,
                              hipStream_t stream) {
    const float* x    = (const float*)d_in[0];
    const float* emb  = (const float*)d_in[1];
    const float* W_l  = (const float*)d_in[2];
    const float* b_l  = (const float*)d_in[3];
    const float* W_r  = (const float*)d_in[4];
    const float* b_r  = (const float*)d_in[5];
    const int*   ei   = (const int*)d_in[6];
    const int*   ew   = (const int*)d_in[7];

    float* out = (float*)d_out;

    // workspace layout
    char* ws = (char*)d_ws;
    float*    wtl       = (float*)ws;   ws += D * D * sizeof(float);
    float*    wtr       = (float*)ws;   ws += D * D * sizeof(float);
    int*      counts    = (int*)ws;     ws += N_NODES * sizeof(int);
    int*      offs      = (int*)ws;     ws += (N_NODES + 1) * sizeof(int);
    int*      woff      = (int*)ws;     ws += N_NODES * sizeof(int);
    int*      blockSums = (int*)ws;     ws += SCAN_BLOCKS * sizeof(int);
    int*      blockOffs = (int*)ws;     ws += SCAN_BLOCKS * sizeof(int);
    unsigned* packed    = (unsigned*)ws; ws += N_EDGES * sizeof(unsigned);
    size_t needed = (size_t)(ws - (char*)d_ws);

    transpose_w<<<(D * D + 255) / 256, 256, 0, stream>>>(W_l, W_r, wtl, wtr);

    if (ws_size >= needed) {
        // CSR build + gather aggregate (no float atomics)
        zero_ints<<<(N_NODES + 255) / 256, 256, 0, stream>>>(counts, N_NODES);
        hist_kernel<<<(N_EDGES + 255) / 256, 256, 0, stream>>>(ei, counts);
        scan_phase1<<<SCAN_BLOCKS, 256, 0, stream>>>(counts, blockSums);
        scan_phase2<<<1, 256, 0, stream>>>(blockSums, blockOffs, offs);
        scan_phase3<<<SCAN_BLOCKS, 256, 0, stream>>>(counts, blockOffs, offs, woff);
        pack_kernel<<<(N_EDGES + 255) / 256, 256, 0, stream>>>(ei, ew, woff, packed);
        aggregate_kernel<<<(N_NODES + 3) / 4, 256, 0, stream>>>(x, emb, offs, packed, out);
    } else {
        // fallback: atomic scatter into d_out
        int n4 = N_NODES * D / 4;
        zero_kernel<<<(n4 + 255) / 256, 256, 0, stream>>>((float4*)out, n4);
        long long work = (long long)N_EDGES * 32;
        scatter_kernel<<<(int)((work + 255) / 256), 256, 0, stream>>>(x, emb, ei, ew, out);
    }

    gemm_kernel<<<(N_NODES + 31) / 32, 256, 0, stream>>>(x, out, wtl, wtr, b_l, b_r);
}

// Round 4
// 169.282 us; speedup vs baseline: 6.6230x; 1.4020x over previous
//
#include <hip/hip_runtime.h>

#define N_NODES 50000
#define N_EDGES 600000
#define D 128
#define SCAN_BLOCKS ((N_NODES + 255) / 256)   // 196

typedef __attribute__((ext_vector_type(8))) short short8v;
typedef __attribute__((ext_vector_type(4))) float f32x4;

__device__ __forceinline__ unsigned short f2bf(float v) {
    unsigned u = __builtin_bit_cast(unsigned, v);
    u += 0x7FFFu + ((u >> 16) & 1u);          // round-to-nearest-even
    return (unsigned short)(u >> 16);
}
__device__ __forceinline__ float bf2f(unsigned short h) {
    unsigned u = ((unsigned)h) << 16;
    return __builtin_bit_cast(float, u);
}

// ============================== CSR-build path ==============================

__global__ void zero_ints(int* __restrict__ p, int n) {
    int i = blockIdx.x * blockDim.x + threadIdx.x;
    if (i < n) p[i] = 0;
}

__global__ __launch_bounds__(256) void hist_kernel(
    const int* __restrict__ ei, int* __restrict__ counts)
{
    int e = blockIdx.x * blockDim.x + threadIdx.x;
    if (e >= N_EDGES) return;
    atomicAdd(&counts[ei[N_EDGES + e]], 1);
}

__global__ __launch_bounds__(256) void scan_phase1(
    const int* __restrict__ counts, int* __restrict__ blockSums)
{
    int i = blockIdx.x * 256 + threadIdx.x;
    int v = (i < N_NODES) ? counts[i] : 0;
#pragma unroll
    for (int off = 32; off > 0; off >>= 1) v += __shfl_down(v, off, 64);
    __shared__ int wsum[4];
    int lane = threadIdx.x & 63, wid = threadIdx.x >> 6;
    if (lane == 0) wsum[wid] = v;
    __syncthreads();
    if (threadIdx.x == 0)
        blockSums[blockIdx.x] = wsum[0] + wsum[1] + wsum[2] + wsum[3];
}

__global__ __launch_bounds__(256) void scan_phase2(
    const int* __restrict__ blockSums, int* __restrict__ blockOffs,
    int* __restrict__ offs)
{
    __shared__ int sh[256];
    int t = threadIdx.x;
    int v = (t < SCAN_BLOCKS) ? blockSums[t] : 0;
    sh[t] = v;
    __syncthreads();
    for (int off = 1; off < 256; off <<= 1) {
        int u = (t >= off) ? sh[t - off] : 0;
        __syncthreads();
        sh[t] += u;
        __syncthreads();
    }
    if (t < SCAN_BLOCKS) blockOffs[t] = sh[t] - v;   // exclusive
    if (t == 0) offs[N_NODES] = N_EDGES;
}

__global__ __launch_bounds__(256) void scan_phase3(
    const int* __restrict__ counts,
    const int* __restrict__ blockOffs,
    int* __restrict__ offs, int* __restrict__ woff)
{
    int t = threadIdx.x;
    int i = blockIdx.x * 256 + t;
    int v = (i < N_NODES) ? counts[i] : 0;
    int lane = t & 63, wid = t >> 6;
    int s = v;
#pragma unroll
    for (int off = 1; off < 64; off <<= 1) {
        int u = __shfl_up(s, off, 64);
        if (lane >= off) s += u;
    }
    __shared__ int wsum[4];
    if (lane == 63) wsum[wid] = s;
    __syncthreads();
    int wadd = 0;
    for (int w = 0; w < wid; w++) wadd += wsum[w];
    if (i < N_NODES) {
        int excl = blockOffs[blockIdx.x] + s + wadd - v;
        offs[i] = excl;
        woff[i] = excl;
    }
}

__global__ __launch_bounds__(256) void pack_kernel(
    const int* __restrict__ ei,
    const int* __restrict__ ew,
    int* __restrict__ woff,
    unsigned* __restrict__ packed)
{
    int e = blockIdx.x * blockDim.x + threadIdx.x;
    if (e >= N_EDGES) return;
    int dst = ei[N_EDGES + e];
    int pos = atomicAdd(&woff[dst], 1);
    packed[pos] = (unsigned)ei[e] | ((unsigned)ew[e] << 16);
}

// one 64-lane wave per node, float2 per lane; prop row written exactly once
__global__ __launch_bounds__(256) void aggregate_kernel(
    const float* __restrict__ x,
    const float* __restrict__ emb,
    const int* __restrict__ offs,
    const unsigned* __restrict__ packed,
    float* __restrict__ prop)   // aliases d_out
{
    int node = blockIdx.x * 4 + (threadIdx.x >> 6);
    if (node >= N_NODES) return;
    int c = (threadIdx.x & 63) * 2;

    int beg = offs[node], end = offs[node + 1];
    float2 acc = make_float2(0.f, 0.f);
    for (int i = beg; i < end; i++) {
        unsigned p = packed[i];
        float2 ev = *(const float2*)(emb + (size_t)(p >> 16) * D + c);
        float2 xv = *(const float2*)(x   + (size_t)(p & 0xFFFFu) * D + c);
        acc.x += ev.x * xv.x;
        acc.y += ev.y * xv.y;
    }
    *(float2*)(prop + (size_t)node * D + c) = acc;
}

// ============================ fallback (atomic) =============================

__global__ void zero_kernel(float4* __restrict__ out, int n4) {
    int i = blockIdx.x * blockDim.x + threadIdx.x;
    int stride = gridDim.x * blockDim.x;
    for (; i < n4; i += stride) out[i] = make_float4(0.f, 0.f, 0.f, 0.f);
}

__global__ __launch_bounds__(256) void scatter_kernel(
    const float* __restrict__ x,
    const float* __restrict__ emb,
    const int*   __restrict__ ei,
    const int*   __restrict__ ew,
    float*       __restrict__ prop)
{
    int gid = blockIdx.x * blockDim.x + threadIdx.x;
    int e = gid >> 5;
    if (e >= N_EDGES) return;
    int d4 = (gid & 31) * 4;
    int src = ei[e];
    int dst = ei[N_EDGES + e];
    int w   = ew[e];
    float4 ev = *(const float4*)(emb + (size_t)w * D + d4);
    float4 xv = *(const float4*)(x + (size_t)src * D + d4);
    float* p = prop + (size_t)dst * D + d4;
    atomicAdd(p + 0, ev.x * xv.x);
    atomicAdd(p + 1, ev.y * xv.y);
    atomicAdd(p + 2, ev.z * xv.z);
    atomicAdd(p + 3, ev.w * xv.w);
}

// ======================= bf16x2-split MFMA GEMM =============================
// out = [x | prop] @ [Wl^T ; Wr^T] + (b_l + b_r),   K = 256, N = 128
// Split:  A ~= Ah + Al,  B ~= Bh + Bl  (bf16 each);
// out ~= Ah@Bh + Al@Bh + Ah@Bl   (lo*lo dropped, ~1e-5).
//
// B is stored transposed as [n][k] -> exactly the original W row-major layout.

__global__ __launch_bounds__(256) void bprep_kernel(
    const float* __restrict__ Wl, const float* __restrict__ Wr,
    unsigned short* __restrict__ Bh, unsigned short* __restrict__ Bl)
{
    int t = blockIdx.x * 256 + threadIdx.x;
    if (t >= 128 * 256) return;
    int n = t >> 8;
    int k = t & 255;
    float w = (k < 128) ? Wl[n * 128 + k] : Wr[n * 128 + (k - 128)];
    unsigned short h = f2bf(w);
    unsigned short l = f2bf(w - bf2f(h));
    Bh[t] = h;
    Bl[t] = l;
}

// Block: 256 thr (4 waves), tile 128 rows x 128 cols. Waves 2x2 -> 64x64 each.
// K-chunks of 32; A converted f32->hi/lo bf16 in-kernel; LDS stride 40 bf16
// (80 B) -> 2-way bank aliasing only (free).
__global__ __launch_bounds__(256) void mfma_gemm(
    const float* __restrict__ x,
    float*       __restrict__ out,          // prop on entry, result on exit
    const unsigned short* __restrict__ Bh,  // [128][256]
    const unsigned short* __restrict__ Bl,
    const float* __restrict__ bl_,
    const float* __restrict__ br_)
{
    __shared__ unsigned short Ah_s[128 * 40];
    __shared__ unsigned short Al_s[128 * 40];
    __shared__ unsigned short Bh_s[128 * 40];
    __shared__ unsigned short Bl_s[128 * 40];

    const int tid  = threadIdx.x;
    const int lane = tid & 63;
    const int wave = tid >> 6;
    const int row0 = blockIdx.x * 128;

    const int wr0 = (wave >> 1) * 64;   // wave row offset in tile
    const int wc0 = (wave & 1) * 64;    // wave col offset in tile
    const int lr  = lane & 15;
    const int lk8 = (lane >> 4) * 8;

    const int srow  = tid >> 1;         // staging row 0..127
    const int skoff = (tid & 1) * 16;   // staging k sub-offset (elements)

    f32x4 acc[4][4];
#pragma unroll
    for (int i = 0; i < 4; i++)
#pragma unroll
        for (int j = 0; j < 4; j++)
            acc[i][j] = (f32x4){0.f, 0.f, 0.f, 0.f};

    for (int kc = 0; kc < 8; ++kc) {
        const int kbase = kc * 32;
        // ---- stage A (x for k<128, prop for k>=128), split to hi/lo ----
        {
            const float* Asrc = (kbase < 128) ? x : out;
            const int acol = (kbase & 127) + skoff;
            const int grow = row0 + srow;
            float v[16];
            if (grow < N_NODES) {
                const float4* p = (const float4*)(Asrc + (size_t)grow * D + acol);
#pragma unroll
                for (int q = 0; q < 4; q++) {
                    float4 f = p[q];
                    v[q*4+0] = f.x; v[q*4+1] = f.y; v[q*4+2] = f.z; v[q*4+3] = f.w;
                }
            } else {
#pragma unroll
                for (int q = 0; q < 16; q++) v[q] = 0.f;
            }
            short8v h0, h1, l0, l1;
#pragma unroll
            for (int q = 0; q < 8; q++) {
                unsigned short h = f2bf(v[q]);
                h0[q] = (short)h;
                l0[q] = (short)f2bf(v[q] - bf2f(h));
            }
#pragma unroll
            for (int q = 0; q < 8; q++) {
                unsigned short h = f2bf(v[q + 8]);
                h1[q] = (short)h;
                l1[q] = (short)f2bf(v[q + 8] - bf2f(h));
            }
            *(short8v*)(Ah_s + srow * 40 + skoff)     = h0;
            *(short8v*)(Ah_s + srow * 40 + skoff + 8) = h1;
            *(short8v*)(Al_s + srow * 40 + skoff)     = l0;
            *(short8v*)(Al_s + srow * 40 + skoff + 8) = l1;
        }
        // ---- stage B (pre-split bf16 from ws) ----
        {
            const size_t boff = (size_t)srow * 256 + kbase + skoff;
            short8v bh0 = *(const short8v*)(Bh + boff);
            short8v bh1 = *(const short8v*)(Bh + boff + 8);
            short8v bl0 = *(const short8v*)(Bl + boff);
            short8v bl1 = *(const short8v*)(Bl + boff + 8);
            *(short8v*)(Bh_s + srow * 40 + skoff)     = bh0;
            *(short8v*)(Bh_s + srow * 40 + skoff + 8) = bh1;
            *(short8v*)(Bl_s + srow * 40 + skoff)     = bl0;
            *(short8v*)(Bl_s + srow * 40 + skoff + 8) = bl1;
        }
        __syncthreads();
        // ---- compute: 3 precision segments, 2x... 4rt x 4ct frags ----
        short8v afh[4], afl[4];
#pragma unroll
        for (int rt = 0; rt < 4; rt++) {
            int ar = wr0 + rt * 16 + lr;
            afh[rt] = *(const short8v*)(Ah_s + ar * 40 + lk8);
            afl[rt] = *(const short8v*)(Al_s + ar * 40 + lk8);
        }
#pragma unroll
        for (int ct = 0; ct < 4; ct++) {
            int bc = wc0 + ct * 16 + lr;
            short8v bfh = *(const short8v*)(Bh_s + bc * 40 + lk8);
            short8v bfl = *(const short8v*)(Bl_s + bc * 40 + lk8);
#pragma unroll
            for (int rt = 0; rt < 4; rt++)
                acc[rt][ct] = __builtin_amdgcn_mfma_f32_16x16x32_bf16(afh[rt], bfh, acc[rt][ct], 0, 0, 0);
#pragma unroll
            for (int rt = 0; rt < 4; rt++)
                acc[rt][ct] = __builtin_amdgcn_mfma_f32_16x16x32_bf16(afl[rt], bfh, acc[rt][ct], 0, 0, 0);
#pragma unroll
            for (int rt = 0; rt < 4; rt++)
                acc[rt][ct] = __builtin_amdgcn_mfma_f32_16x16x32_bf16(afh[rt], bfl, acc[rt][ct], 0, 0, 0);
        }
        __syncthreads();
    }

    // ---- epilogue: bias + store (C/D: col=lane&15, row=(lane>>4)*4+reg) ----
    const int drow = (lane >> 4) * 4;
#pragma unroll
    for (int ct = 0; ct < 4; ct++) {
        int col = wc0 + ct * 16 + lr;
        float bias = bl_[col] + br_[col];
#pragma unroll
        for (int rt = 0; rt < 4; rt++) {
#pragma unroll
            for (int r = 0; r < 4; r++) {
                int grow = row0 + wr0 + rt * 16 + drow + r;
                if (grow < N_NODES)
                    out[(size_t)grow * D + col] = acc[rt][ct][r] + bias;
            }
        }
    }
}

// ============================================================================
extern "C" void kernel_launch(void* const* d_in, const int* in_sizes, int n_in,
                              void* d_out, int out_size, void* d_ws, size_t ws_size,
                              hipStream_t stream) {
    const float* x    = (const float*)d_in[0];
    const float* emb  = (const float*)d_in[1];
    const float* W_l  = (const float*)d_in[2];
    const float* b_l  = (const float*)d_in[3];
    const float* W_r  = (const float*)d_in[4];
    const float* b_r  = (const float*)d_in[5];
    const int*   ei   = (const int*)d_in[6];
    const int*   ew   = (const int*)d_in[7];

    float* out = (float*)d_out;

    // workspace layout
    char* wsp = (char*)d_ws;
    unsigned short* Bh = (unsigned short*)wsp; wsp += 128 * 256 * sizeof(unsigned short);
    unsigned short* Bl = (unsigned short*)wsp; wsp += 128 * 256 * sizeof(unsigned short);
    int*      counts    = (int*)wsp;     wsp += N_NODES * sizeof(int);
    int*      offs      = (int*)wsp;     wsp += (N_NODES + 1) * sizeof(int);
    int*      woff      = (int*)wsp;     wsp += N_NODES * sizeof(int);
    int*      blockSums = (int*)wsp;     wsp += SCAN_BLOCKS * sizeof(int);
    int*      blockOffs = (int*)wsp;     wsp += SCAN_BLOCKS * sizeof(int);
    unsigned* packed    = (unsigned*)wsp; wsp += N_EDGES * sizeof(unsigned);
    size_t needed = (size_t)(wsp - (char*)d_ws);

    // pre-split weights into bf16 hi/lo (B^T layout == original W layout)
    bprep_kernel<<<(128 * 256 + 255) / 256, 256, 0, stream>>>(W_l, W_r, Bh, Bl);

    if (ws_size >= needed) {
        // CSR build + gather aggregate (no float atomics)
        zero_ints<<<(N_NODES + 255) / 256, 256, 0, stream>>>(counts, N_NODES);
        hist_kernel<<<(N_EDGES + 255) / 256, 256, 0, stream>>>(ei, counts);
        scan_phase1<<<SCAN_BLOCKS, 256, 0, stream>>>(counts, blockSums);
        scan_phase2<<<1, 256, 0, stream>>>(blockSums, blockOffs, offs);
        scan_phase3<<<SCAN_BLOCKS, 256, 0, stream>>>(counts, blockOffs, offs, woff);
        pack_kernel<<<(N_EDGES + 255) / 256, 256, 0, stream>>>(ei, ew, woff, packed);
        aggregate_kernel<<<(N_NODES + 3) / 4, 256, 0, stream>>>(x, emb, offs, packed, out);
    } else {
        // fallback: atomic scatter into d_out
        int n4 = N_NODES * D / 4;
        zero_kernel<<<(n4 + 255) / 256, 256, 0, stream>>>((float4*)out, n4);
        long long work = (long long)N_EDGES * 32;
        scatter_kernel<<<(int)((work + 255) / 256), 256, 0, stream>>>(x, emb, ei, ew, out);
    }

    // fused dual GEMM + bias via bf16x2-split MFMA, in-place on d_out
    mfma_gemm<<<(N_NODES + 127) / 128, 256, 0, stream>>>(x, out, Bh, Bl, b_l, b_r);
}

// Round 5
// 144.513 us; speedup vs baseline: 7.7581x; 1.1714x over previous
//
#include <hip/hip_runtime.h>

#define N_NODES 50000
#define N_EDGES 600000
#define D 128
#define SCAN_BLOCKS ((N_NODES + 255) / 256)   // 196

typedef __attribute__((ext_vector_type(8))) short short8v;
typedef __attribute__((ext_vector_type(4))) float f32x4;

__device__ __forceinline__ unsigned short f2bf(float v) {
    unsigned u = __builtin_bit_cast(unsigned, v);
    u += 0x7FFFu + ((u >> 16) & 1u);          // round-to-nearest-even
    return (unsigned short)(u >> 16);
}
__device__ __forceinline__ float bf2f(unsigned short h) {
    unsigned u = ((unsigned)h) << 16;
    return __builtin_bit_cast(float, u);
}

// ============================== CSR-build path ==============================

__global__ void zero_ints(int* __restrict__ p, int n) {
    int i = blockIdx.x * blockDim.x + threadIdx.x;
    if (i < n) p[i] = 0;
}

__global__ __launch_bounds__(256) void hist_kernel(
    const int* __restrict__ ei, int* __restrict__ counts)
{
    int e = blockIdx.x * blockDim.x + threadIdx.x;
    if (e >= N_EDGES) return;
    atomicAdd(&counts[ei[N_EDGES + e]], 1);
}

__global__ __launch_bounds__(256) void scan_phase1(
    const int* __restrict__ counts, int* __restrict__ blockSums)
{
    int i = blockIdx.x * 256 + threadIdx.x;
    int v = (i < N_NODES) ? counts[i] : 0;
#pragma unroll
    for (int off = 32; off > 0; off >>= 1) v += __shfl_down(v, off, 64);
    __shared__ int wsum[4];
    int lane = threadIdx.x & 63, wid = threadIdx.x >> 6;
    if (lane == 0) wsum[wid] = v;
    __syncthreads();
    if (threadIdx.x == 0)
        blockSums[blockIdx.x] = wsum[0] + wsum[1] + wsum[2] + wsum[3];
}

__global__ __launch_bounds__(256) void scan_phase2(
    const int* __restrict__ blockSums, int* __restrict__ blockOffs,
    int* __restrict__ offs)
{
    __shared__ int sh[256];
    int t = threadIdx.x;
    int v = (t < SCAN_BLOCKS) ? blockSums[t] : 0;
    sh[t] = v;
    __syncthreads();
    for (int off = 1; off < 256; off <<= 1) {
        int u = (t >= off) ? sh[t - off] : 0;
        __syncthreads();
        sh[t] += u;
        __syncthreads();
    }
    if (t < SCAN_BLOCKS) blockOffs[t] = sh[t] - v;   // exclusive
    if (t == 0) offs[N_NODES] = N_EDGES;
}

__global__ __launch_bounds__(256) void scan_phase3(
    const int* __restrict__ counts,
    const int* __restrict__ blockOffs,
    int* __restrict__ offs, int* __restrict__ woff)
{
    int t = threadIdx.x;
    int i = blockIdx.x * 256 + t;
    int v = (i < N_NODES) ? counts[i] : 0;
    int lane = t & 63, wid = t >> 6;
    int s = v;
#pragma unroll
    for (int off = 1; off < 64; off <<= 1) {
        int u = __shfl_up(s, off, 64);
        if (lane >= off) s += u;
    }
    __shared__ int wsum[4];
    if (lane == 63) wsum[wid] = s;
    __syncthreads();
    int wadd = 0;
    for (int w = 0; w < wid; w++) wadd += wsum[w];
    if (i < N_NODES) {
        int excl = blockOffs[blockIdx.x] + s + wadd - v;
        offs[i] = excl;
        woff[i] = excl;
    }
}

__global__ __launch_bounds__(256) void pack_kernel(
    const int* __restrict__ ei,
    const int* __restrict__ ew,
    int* __restrict__ woff,
    unsigned* __restrict__ packed)
{
    int e = blockIdx.x * blockDim.x + threadIdx.x;
    if (e >= N_EDGES) return;
    int dst = ei[N_EDGES + e];
    int pos = atomicAdd(&woff[dst], 1);
    packed[pos] = (unsigned)ei[e] | ((unsigned)ew[e] << 16);
}

// one 64-lane wave per node, float2 per lane; prop row written exactly once.
// Edge loop unrolled x4 with all 4 x-row loads issued before the FMAs -> 4
// outstanding VMEM ops per wave (memory-level parallelism).
__global__ __launch_bounds__(256) void aggregate_kernel(
    const float* __restrict__ x,
    const float* __restrict__ emb,
    const int* __restrict__ offs,
    const unsigned* __restrict__ packed,
    float* __restrict__ prop)   // aliases d_out
{
    int node = blockIdx.x * 4 + (threadIdx.x >> 6);
    if (node >= N_NODES) return;
    int c = (threadIdx.x & 63) * 2;

    int beg = offs[node], end = offs[node + 1];
    float2 acc = make_float2(0.f, 0.f);

    int i = beg;
    for (; i + 4 <= end; i += 4) {
        unsigned p0 = packed[i + 0];
        unsigned p1 = packed[i + 1];
        unsigned p2 = packed[i + 2];
        unsigned p3 = packed[i + 3];
        float2 x0 = *(const float2*)(x + (size_t)(p0 & 0xFFFFu) * D + c);
        float2 x1 = *(const float2*)(x + (size_t)(p1 & 0xFFFFu) * D + c);
        float2 x2 = *(const float2*)(x + (size_t)(p2 & 0xFFFFu) * D + c);
        float2 x3 = *(const float2*)(x + (size_t)(p3 & 0xFFFFu) * D + c);
        float2 e0 = *(const float2*)(emb + (size_t)(p0 >> 16) * D + c);
        float2 e1 = *(const float2*)(emb + (size_t)(p1 >> 16) * D + c);
        float2 e2 = *(const float2*)(emb + (size_t)(p2 >> 16) * D + c);
        float2 e3 = *(const float2*)(emb + (size_t)(p3 >> 16) * D + c);
        acc.x += e0.x * x0.x; acc.y += e0.y * x0.y;
        acc.x += e1.x * x1.x; acc.y += e1.y * x1.y;
        acc.x += e2.x * x2.x; acc.y += e2.y * x2.y;
        acc.x += e3.x * x3.x; acc.y += e3.y * x3.y;
    }
    for (; i < end; i++) {
        unsigned p = packed[i];
        float2 ev = *(const float2*)(emb + (size_t)(p >> 16) * D + c);
        float2 xv = *(const float2*)(x   + (size_t)(p & 0xFFFFu) * D + c);
        acc.x += ev.x * xv.x;
        acc.y += ev.y * xv.y;
    }
    *(float2*)(prop + (size_t)node * D + c) = acc;
}

// ============================ fallback (atomic) =============================

__global__ void zero_kernel(float4* __restrict__ out, int n4) {
    int i = blockIdx.x * blockDim.x + threadIdx.x;
    int stride = gridDim.x * blockDim.x;
    for (; i < n4; i += stride) out[i] = make_float4(0.f, 0.f, 0.f, 0.f);
}

__global__ __launch_bounds__(256) void scatter_kernel(
    const float* __restrict__ x,
    const float* __restrict__ emb,
    const int*   __restrict__ ei,
    const int*   __restrict__ ew,
    float*       __restrict__ prop)
{
    int gid = blockIdx.x * blockDim.x + threadIdx.x;
    int e = gid >> 5;
    if (e >= N_EDGES) return;
    int d4 = (gid & 31) * 4;
    int src = ei[e];
    int dst = ei[N_EDGES + e];
    int w   = ew[e];
    float4 ev = *(const float4*)(emb + (size_t)w * D + d4);
    float4 xv = *(const float4*)(x + (size_t)src * D + d4);
    float* p = prop + (size_t)dst * D + d4;
    atomicAdd(p + 0, ev.x * xv.x);
    atomicAdd(p + 1, ev.y * xv.y);
    atomicAdd(p + 2, ev.z * xv.z);
    atomicAdd(p + 3, ev.w * xv.w);
}

// ======================= bf16x2-split MFMA GEMM =============================
// out = [x | prop] @ [Wl^T ; Wr^T] + (b_l + b_r),   K = 256, N = 128
// Split:  A ~= Ah + Al,  B ~= Bh + Bl  (bf16 each);
// out ~= Ah@Bh + Al@Bh + Ah@Bl   (lo*lo dropped, ~1e-5).

__global__ __launch_bounds__(256) void bprep_kernel(
    const float* __restrict__ Wl, const float* __restrict__ Wr,
    unsigned short* __restrict__ Bh, unsigned short* __restrict__ Bl)
{
    int t = blockIdx.x * 256 + threadIdx.x;
    if (t >= 128 * 256) return;
    int n = t >> 8;
    int k = t & 255;
    float w = (k < 128) ? Wl[n * 128 + k] : Wr[n * 128 + (k - 128)];
    unsigned short h = f2bf(w);
    unsigned short l = f2bf(w - bf2f(h));
    Bh[t] = h;
    Bl[t] = l;
}

__global__ __launch_bounds__(256) void mfma_gemm(
    const float* __restrict__ x,
    float*       __restrict__ out,          // prop on entry, result on exit
    const unsigned short* __restrict__ Bh,  // [128][256]
    const unsigned short* __restrict__ Bl,
    const float* __restrict__ bl_,
    const float* __restrict__ br_)
{
    __shared__ unsigned short Ah_s[128 * 40];
    __shared__ unsigned short Al_s[128 * 40];
    __shared__ unsigned short Bh_s[128 * 40];
    __shared__ unsigned short Bl_s[128 * 40];

    const int tid  = threadIdx.x;
    const int lane = tid & 63;
    const int wave = tid >> 6;
    const int row0 = blockIdx.x * 128;

    const int wr0 = (wave >> 1) * 64;
    const int wc0 = (wave & 1) * 64;
    const int lr  = lane & 15;
    const int lk8 = (lane >> 4) * 8;

    const int srow  = tid >> 1;
    const int skoff = (tid & 1) * 16;

    f32x4 acc[4][4];
#pragma unroll
    for (int i = 0; i < 4; i++)
#pragma unroll
        for (int j = 0; j < 4; j++)
            acc[i][j] = (f32x4){0.f, 0.f, 0.f, 0.f};

    for (int kc = 0; kc < 8; ++kc) {
        const int kbase = kc * 32;
        {
            const float* Asrc = (kbase < 128) ? x : out;
            const int acol = (kbase & 127) + skoff;
            const int grow = row0 + srow;
            float v[16];
            if (grow < N_NODES) {
                const float4* p = (const float4*)(Asrc + (size_t)grow * D + acol);
#pragma unroll
                for (int q = 0; q < 4; q++) {
                    float4 f = p[q];
                    v[q*4+0] = f.x; v[q*4+1] = f.y; v[q*4+2] = f.z; v[q*4+3] = f.w;
                }
            } else {
#pragma unroll
                for (int q = 0; q < 16; q++) v[q] = 0.f;
            }
            short8v h0, h1, l0, l1;
#pragma unroll
            for (int q = 0; q < 8; q++) {
                unsigned short h = f2bf(v[q]);
                h0[q] = (short)h;
                l0[q] = (short)f2bf(v[q] - bf2f(h));
            }
#pragma unroll
            for (int q = 0; q < 8; q++) {
                unsigned short h = f2bf(v[q + 8]);
                h1[q] = (short)h;
                l1[q] = (short)f2bf(v[q + 8] - bf2f(h));
            }
            *(short8v*)(Ah_s + srow * 40 + skoff)     = h0;
            *(short8v*)(Ah_s + srow * 40 + skoff + 8) = h1;
            *(short8v*)(Al_s + srow * 40 + skoff)     = l0;
            *(short8v*)(Al_s + srow * 40 + skoff + 8) = l1;
        }
        {
            const size_t boff = (size_t)srow * 256 + kbase + skoff;
            short8v bh0 = *(const short8v*)(Bh + boff);
            short8v bh1 = *(const short8v*)(Bh + boff + 8);
            short8v bl0 = *(const short8v*)(Bl + boff);
            short8v bl1 = *(const short8v*)(Bl + boff + 8);
            *(short8v*)(Bh_s + srow * 40 + skoff)     = bh0;
            *(short8v*)(Bh_s + srow * 40 + skoff + 8) = bh1;
            *(short8v*)(Bl_s + srow * 40 + skoff)     = bl0;
            *(short8v*)(Bl_s + srow * 40 + skoff + 8) = bl1;
        }
        __syncthreads();
        short8v afh[4], afl[4];
#pragma unroll
        for (int rt = 0; rt < 4; rt++) {
            int ar = wr0 + rt * 16 + lr;
            afh[rt] = *(const short8v*)(Ah_s + ar * 40 + lk8);
            afl[rt] = *(const short8v*)(Al_s + ar * 40 + lk8);
        }
#pragma unroll
        for (int ct = 0; ct < 4; ct++) {
            int bc = wc0 + ct * 16 + lr;
            short8v bfh = *(const short8v*)(Bh_s + bc * 40 + lk8);
            short8v bfl = *(const short8v*)(Bl_s + bc * 40 + lk8);
#pragma unroll
            for (int rt = 0; rt < 4; rt++)
                acc[rt][ct] = __builtin_amdgcn_mfma_f32_16x16x32_bf16(afh[rt], bfh, acc[rt][ct], 0, 0, 0);
#pragma unroll
            for (int rt = 0; rt < 4; rt++)
                acc[rt][ct] = __builtin_amdgcn_mfma_f32_16x16x32_bf16(afl[rt], bfh, acc[rt][ct], 0, 0, 0);
#pragma unroll
            for (int rt = 0; rt < 4; rt++)
                acc[rt][ct] = __builtin_amdgcn_mfma_f32_16x16x32_bf16(afh[rt], bfl, acc[rt][ct], 0, 0, 0);
        }
        __syncthreads();
    }

    const int drow = (lane >> 4) * 4;
#pragma unroll
    for (int ct = 0; ct < 4; ct++) {
        int col = wc0 + ct * 16 + lr;
        float bias = bl_[col] + br_[col];
#pragma unroll
        for (int rt = 0; rt < 4; rt++) {
#pragma unroll
            for (int r = 0; r < 4; r++) {
                int grow = row0 + wr0 + rt * 16 + drow + r;
                if (grow < N_NODES)
                    out[(size_t)grow * D + col] = acc[rt][ct][r] + bias;
            }
        }
    }
}

// ============================================================================
extern "C" void kernel_launch(void* const* d_in, const int* in_sizes, int n_in,
                              void* d_out, int out_size, void* d_ws, size_t ws_size,
                              hipStream_t stream) {
    const float* x    = (const float*)d_in[0];
    const float* emb  = (const float*)d_in[1];
    const float* W_l  = (const float*)d_in[2];
    const float* b_l  = (const float*)d_in[3];
    const float* W_r  = (const float*)d_in[4];
    const float* b_r  = (const float*)d_in[5];
    const int*   ei   = (const int*)d_in[6];
    const int*   ew   = (const int*)d_in[7];

    float* out = (float*)d_out;

    char* wsp = (char*)d_ws;
    unsigned short* Bh = (unsigned short*)wsp; wsp += 128 * 256 * sizeof(unsigned short);
    unsigned short* Bl = (unsigned short*)wsp; wsp += 128 * 256 * sizeof(unsigned short);
    int*      counts    = (int*)wsp;     wsp += N_NODES * sizeof(int);
    int*      offs      = (int*)wsp;     wsp += (N_NODES + 1) * sizeof(int);
    int*      woff      = (int*)wsp;     wsp += N_NODES * sizeof(int);
    int*      blockSums = (int*)wsp;     wsp += SCAN_BLOCKS * sizeof(int);
    int*      blockOffs = (int*)wsp;     wsp += SCAN_BLOCKS * sizeof(int);
    unsigned* packed    = (unsigned*)wsp; wsp += N_EDGES * sizeof(unsigned);
    size_t needed = (size_t)(wsp - (char*)d_ws);

    bprep_kernel<<<(128 * 256 + 255) / 256, 256, 0, stream>>>(W_l, W_r, Bh, Bl);

    if (ws_size >= needed) {
        zero_ints<<<(N_NODES + 255) / 256, 256, 0, stream>>>(counts, N_NODES);
        hist_kernel<<<(N_EDGES + 255) / 256, 256, 0, stream>>>(ei, counts);
        scan_phase1<<<SCAN_BLOCKS, 256, 0, stream>>>(counts, blockSums);
        scan_phase2<<<1, 256, 0, stream>>>(blockSums, blockOffs, offs);
        scan_phase3<<<SCAN_BLOCKS, 256, 0, stream>>>(counts, blockOffs, offs, woff);
        pack_kernel<<<(N_EDGES + 255) / 256, 256, 0, stream>>>(ei, ew, woff, packed);
        aggregate_kernel<<<(N_NODES + 3) / 4, 256, 0, stream>>>(x, emb, offs, packed, out);
    } else {
        int n4 = N_NODES * D / 4;
        zero_kernel<<<(n4 + 255) / 256, 256, 0, stream>>>((float4*)out, n4);
        long long work = (long long)N_EDGES * 32;
        scatter_kernel<<<(int)((work + 255) / 256), 256, 0, stream>>>(x, emb, ei, ew, out);
    }

    mfma_gemm<<<(N_NODES + 127) / 128, 256, 0, stream>>>(x, out, Bh, Bl, b_l, b_r);
}